// Round 18
// baseline (940.498 us; speedup 1.0000x reference)
//
#include <hip/hip_runtime.h>

#define ALPHA 0.2f
__device__ __forceinline__ float lrelu_f(float x){ return x>0.f ? x : ALPHA*x; }
__device__ __forceinline__ float4 zero4(){ float4 z; z.x=z.y=z.z=z.w=0.f; return z; }

// XCD-chunk swizzle: bijective iff grid%8==0; identity fallback otherwise.
__device__ __forceinline__ int swz_bid(){
  int nb = gridDim.x, b = blockIdx.x;
  return ((nb & 7)==0) ? ((b & 7)*(nb>>3) + (b>>3)) : b;
}

// ============ enc1 tiled: 3x3 s2 SAME, NHWC(3ch) -> NHWC [n,128,128,32] (r15) ============
template<int H,int W>   // 256,256
__global__ __launch_bounds__(256) void enc1_tiled_k(const float* __restrict__ in,
    const float* __restrict__ w, const float* __restrict__ bias, float* __restrict__ out){
  constexpr int Ho=H/2, Wo=W/2, COUT=32, XL=Wo, ROWS=2, IR=5, EC=XL+1, OC=XL;
  constexpr int WF4 = 9*3*(COUT/4);              // 216
  constexpr int TF4 = IR*EC + IR*OC;             // 1285
  constexpr int OUTF4 = ROWS*XL*(COUT/4);        // 2048
  constexpr int LDSF4 = (TF4+WF4 > OUTF4) ? TF4+WF4 : OUTF4;
  __shared__ float4 lds[LDSF4];
  float4* tE = lds; float4* tO = lds + IR*EC; float4* wch = lds + TF4; float4* outb = lds;

  int lb = swz_bid();
  constexpr int GYI = Ho/ROWS;                   // 64
  int yg = lb % GYI; int n = lb / GYI;
  int y0 = yg*ROWS;
  int x = threadIdx.x & (XL-1);
  int row = threadIdx.x >> 7;

  constexpr int NP = IR*(W+1);
  for (int i=threadIdx.x; i<NP; i+=256){
    int prow = i/(W+1), pcol = i%(W+1);
    int iy = 2*y0 + prow;
    bool ok = (iy<H) && (pcol<W);
    const float* sp = in + (((size_t)n*H + (ok?iy:0))*W + (ok?pcol:0))*3;
    float4 a; a.x = ok?sp[0]:0.f; a.y = ok?sp[1]:0.f; a.z = ok?sp[2]:0.f; a.w = 0.f;
    int j = pcol>>1;
    if (pcol&1) tO[prow*OC + j] = a; else tE[prow*EC + j] = a;
  }
  for (int i=threadIdx.x; i<WF4; i+=256) wch[i] = *(const float4*)(w + (size_t)i*4);
  __syncthreads();

  float acc[COUT];
  #pragma unroll
  for (int f=0;f<COUT/4;f++){
    float4 bv = *(const float4*)(bias + f*4);
    acc[f*4+0]=bv.x; acc[f*4+1]=bv.y; acc[f*4+2]=bv.z; acc[f*4+3]=bv.w;
  }

  #pragma unroll
  for (int ky=0;ky<3;ky++){
    int trow = 2*row + ky;
    #pragma unroll
    for (int kx=0;kx<3;kx++){
      int j = x + (kx==2 ? 1 : 0);
      float4 a = (kx==1) ? tO[trow*OC + j] : tE[trow*EC + j];
      float vs[3] = {a.x, a.y, a.z};
      int tap = ky*3+kx;
      #pragma unroll
      for (int ci=0;ci<3;ci++){
        float v = vs[ci];
        const float4* wp = wch + (tap*3+ci)*(COUT/4);
        #pragma unroll
        for (int f=0;f<COUT/4;f++){
          float4 wv = wp[f];
          acc[f*4+0] += v*wv.x; acc[f*4+1] += v*wv.y;
          acc[f*4+2] += v*wv.z; acc[f*4+3] += v*wv.w;
        }
      }
    }
  }

  __syncthreads();
  int px = row*XL + x;
  #pragma unroll
  for (int f=0;f<COUT/4;f++){
    float4 r;
    r.x=lrelu_f(acc[f*4+0]); r.y=lrelu_f(acc[f*4+1]);
    r.z=lrelu_f(acc[f*4+2]); r.w=lrelu_f(acc[f*4+3]);
    outb[px*(COUT/4) + (f ^ (x & 7))] = r;
  }
  __syncthreads();
  const size_t obase = (((size_t)n*Ho + y0)*(size_t)Wo)*COUT;
  for (int L=threadIdx.x; L<OUTF4; L+=256){
    int p = L/(COUT/4); int sraw = L%(COUT/4);
    int xx = p & (XL-1);
    float4 v = outb[p*(COUT/4) + (sraw ^ (xx & 7))];
    *(float4*)(out + obase + (size_t)L*4) = v;
  }
}

// ============ enc2/enc3 tiled TX=2: 3x3 s2 SAME, NHWC in/out, channel-chunked (r15) ============
template<int H,int W,int CIN,int COUT,int TO,int TX>
__global__ __launch_bounds__(256) void conv3x3_s2_tiled_k(const float* __restrict__ in,
    const float* __restrict__ w, const float* __restrict__ bias, float* __restrict__ out){
  constexpr int Ho=H/2, Wo=W/2, XL=Wo, XC=XL/TX, OBG=COUT/TO, ROWS=256/(XC*OBG);
  static_assert(ROWS==2 && XC*ROWS*OBG==256, "geometry");
  constexpr int IR = 5, EC = XL+1, OC = XL, CC = CIN/8;
  constexpr int WF4 = 9*8*(COUT/4);
  constexpr int TF4 = 2*IR*EC + 2*IR*OC;
  constexpr int OUTF4 = ROWS*XL*(COUT/4);
  constexpr int LDSF4 = (TF4+WF4 > OUTF4) ? TF4+WF4 : OUTF4;
  __shared__ float4 lds[LDSF4];
  float4* tE = lds;                       // [2][IR][EC]
  float4* tO = lds + 2*IR*EC;             // [2][IR][OC]
  float4* wch = lds + TF4;                // [9*8][COUT/4]
  float4* outb = lds;

  int lb = swz_bid();
  constexpr int GYI = Ho/ROWS;
  int yg = lb % GYI; int n = lb / GYI;
  int y0 = yg*ROWS;
  int xc = threadIdx.x % XC;
  int r = threadIdx.x / XC;
  int row = r % ROWS, ob = r / ROWS;      // ob wave-uniform or 2-way (free broadcast)

  float acc[TX][TO];
  #pragma unroll
  for (int f=0;f<TO/4;f++){
    float4 bv = *(const float4*)(bias + ob*TO + f*4);
    #pragma unroll
    for (int t=0;t<TX;t++){
      acc[t][f*4+0]=bv.x; acc[t][f*4+1]=bv.y; acc[t][f*4+2]=bv.z; acc[t][f*4+3]=bv.w;
    }
  }

  constexpr int NP = IR*(W+1);
  for (int cc=0; cc<CC; ++cc){
    __syncthreads();
    for (int i=threadIdx.x; i<NP; i+=256){
      int prow = i/(W+1), pcol = i%(W+1);
      int iy = 2*y0 + prow;
      bool ok = (iy<H) && (pcol<W);
      const float* sp = in + (((size_t)n*H + (ok?iy:0))*W + (ok?pcol:0))*CIN + cc*8;
      float4 a0 = ok ? *(const float4*)sp     : zero4();
      float4 a1 = ok ? *(const float4*)(sp+4) : zero4();
      int j = pcol>>1;
      if (pcol&1){ tO[(0*IR+prow)*OC + j] = a0; tO[(1*IR+prow)*OC + j] = a1; }
      else       { tE[(0*IR+prow)*EC + j] = a0; tE[(1*IR+prow)*EC + j] = a1; }
    }
    for (int i=threadIdx.x; i<WF4; i+=256){
      int co4 = i % (COUT/4); int rest = i/(COUT/4);   // rest = tap*8+ci
      int ci = rest % 8, tap = rest/8;
      wch[i] = *(const float4*)(w + ((size_t)(tap*CIN + cc*8+ci))*COUT + co4*4);
    }
    __syncthreads();
    #pragma unroll
    for (int ky=0;ky<3;ky++){
      int trow = 2*row + ky;
      #pragma unroll
      for (int kx=0;kx<3;kx++){
        float vs[TX][8];
        #pragma unroll
        for (int t=0;t<TX;t++){
          int j = (xc + t*XC) + (kx==2 ? 1 : 0);
          float4 a0, a1;
          if (kx==1){ a0 = tO[(0*IR+trow)*OC + j]; a1 = tO[(1*IR+trow)*OC + j]; }
          else      { a0 = tE[(0*IR+trow)*EC + j]; a1 = tE[(1*IR+trow)*EC + j]; }
          vs[t][0]=a0.x; vs[t][1]=a0.y; vs[t][2]=a0.z; vs[t][3]=a0.w;
          vs[t][4]=a1.x; vs[t][5]=a1.y; vs[t][6]=a1.z; vs[t][7]=a1.w;
        }
        int tap = ky*3+kx;
        #pragma unroll
        for (int ci=0;ci<8;ci++){
          const float4* wp = wch + (tap*8+ci)*(COUT/4) + ob*(TO/4);
          #pragma unroll
          for (int f=0;f<TO/4;f++){
            float4 wv = wp[f];
            #pragma unroll
            for (int t=0;t<TX;t++){
              float v = vs[t][ci];
              acc[t][f*4+0] += v*wv.x; acc[t][f*4+1] += v*wv.y;
              acc[t][f*4+2] += v*wv.z; acc[t][f*4+3] += v*wv.w;
            }
          }
        }
      }
    }
  }

  __syncthreads();                        // all reads done; outb aliases lds
  #pragma unroll
  for (int t=0;t<TX;t++){
    int x = xc + t*XC;
    int px = row*XL + x;
    #pragma unroll
    for (int f=0;f<TO/4;f++){
      float4 r2;
      r2.x=lrelu_f(acc[t][f*4+0]); r2.y=lrelu_f(acc[t][f*4+1]);
      r2.z=lrelu_f(acc[t][f*4+2]); r2.w=lrelu_f(acc[t][f*4+3]);
      int slot = (ob*(TO/4)+f) ^ (x & 15);
      outb[px*(COUT/4) + slot] = r2;
    }
  }
  __syncthreads();
  const size_t obase = (((size_t)n*Ho + y0)*(size_t)Wo)*COUT;
  for (int L=threadIdx.x; L<OUTF4; L+=256){
    int p = L/(COUT/4); int sraw = L%(COUT/4);
    int xx = p % XL;
    float4 v = outb[p*(COUT/4) + (sraw ^ (xx & 15))];
    *(float4*)(out + obase + (size_t)L*4) = v;
  }
}

// ============ Fused enc4 (1x1 conv 64->32) + VQ; k-loop unrolled x4 (ILP) (r15) ============
template<int TPB,int CIN,int D,int K,int PIXI>
__global__ __launch_bounds__(TPB) void enc4_vq_k(const float* __restrict__ in,
    const float* __restrict__ w, const float* __restrict__ bias,
    const float* __restrict__ cb, float* __restrict__ q, int npix){
  int i = blockIdx.x*TPB + threadIdx.x;
  if (i >= npix) return;
  const float* ip = in + (size_t)i*CIN;
  float z[D];
  #pragma unroll
  for (int d=0; d<D; d++) z[d] = bias[d];
  for (int c=0; c<CIN; c+=4){
    float4 v = *(const float4*)(ip + c);
    #pragma unroll
    for (int d=0; d<D; d++){
      z[d] += v.x * w[(c+0)*D + d];
      z[d] += v.y * w[(c+1)*D + d];
      z[d] += v.z * w[(c+2)*D + d];
      z[d] += v.w * w[(c+3)*D + d];
    }
  }
  float z2 = 0.f;
  #pragma unroll
  for (int d=0; d<D; d++) z2 += z[d]*z[d];

  float bestd[4]; int bestk[4];
  #pragma unroll
  for (int j=0;j<4;j++){ bestd[j]=3.4e38f; bestk[j]=0; }
  for (int k=0; k<K; k+=4){
    float e2a[4]={0.f,0.f,0.f,0.f}, dota[4]={0.f,0.f,0.f,0.f};
    #pragma unroll
    for (int d=0; d<D; d++){
      float zd = z[d];
      float4 cv = *(const float4*)(cb + d*K + k);
      e2a[0]+=cv.x*cv.x; dota[0]+=zd*cv.x;
      e2a[1]+=cv.y*cv.y; dota[1]+=zd*cv.y;
      e2a[2]+=cv.z*cv.z; dota[2]+=zd*cv.z;
      e2a[3]+=cv.w*cv.w; dota[3]+=zd*cv.w;
    }
    #pragma unroll
    for (int j=0;j<4;j++){
      float dist = z2 + e2a[j] - 2.f*dota[j];
      if (dist < bestd[j]){ bestd[j]=dist; bestk[j]=k+j; }   // first-min in residue class
    }
  }
  float best = bestd[0]; int bi = bestk[0];
  #pragma unroll
  for (int j=1;j<4;j++){
    if (bestd[j] < best || (bestd[j] == best && bestk[j] < bi)){ best=bestd[j]; bi=bestk[j]; }
  }

  int n = i / PIXI, pix = i % PIXI;
  #pragma unroll
  for (int p=0; p<D/4; p++){
    float4 f;
    f.x = cb[(4*p+0)*K + bi]; f.y = cb[(4*p+1)*K + bi];
    f.z = cb[(4*p+2)*K + bi]; f.w = cb[(4*p+3)*K + bi];
    *(float4*)(q + ((size_t)(n*(D/4)+p)*PIXI + pix)*4) = f;   // coalesced per plane
  }
}

// ======== Parity-fused deconv 3x3 s2 SAME, BLOCKED in/out; TY rows per thread ========
// TY=2 doubles per-block FMA against the FIXED per-block cost (18KB weight staging,
// barrier, launch) — the amortization that makes dec3 (2x work/block) hit ~78% of
// vector peak while dec2 idles at 39% with the identical body.
template<int TPB,int H,int W,int CIN,int COUT,int TO,int TX,int TY,bool LRELU>
__global__ __launch_bounds__(TPB) void deconv3x3_s2_blk_k(const float* __restrict__ in,
    const float* __restrict__ w, const float* __restrict__ bias, float* __restrict__ out){
  constexpr int Ho=2*H, Wo=2*W, OB=COUT/TO, XB2=W/TX, TYR=TPB/XB2, YG=H/(TYR*TY);
  constexpr int PI=CIN/4, PO=COUT/4;
  constexpr int WN = 9*CIN*TO;
  static_assert(TPB % XB2 == 0 && H % (TYR*TY) == 0, "geometry");
  __shared__ float wlds[WN];

  int lb = swz_bid();
  int ob = lb % OB; int g = lb / OB;
  int yg = g % YG;  int n  = g / YG;
  int xb = threadIdx.x % XB2, yr = threadIdx.x / XB2;
  int yy0 = yg*(TYR*TY) + yr*TY, x0 = xb*TX;   // rows yy0 .. yy0+TY-1

  {
    const int base = ob*TO;
    for (int i = threadIdx.x; i < WN/4; i += TPB){
      int j4 = i % (TO/4); int rest = i / (TO/4);
      ((float4*)wlds)[i] = *(const float4*)(w + (size_t)rest*COUT + base + j4*4);
    }
  }
  __syncthreads();

  float acc[TY][2][2*TX][TO];
  #pragma unroll
  for (int j4=0;j4<TO/4;j4++){
    float4 bv = *(const float4*)(bias + ob*TO + j4*4);
    #pragma unroll
    for (int ty=0;ty<TY;ty++)
      #pragma unroll
      for (int py=0;py<2;py++)
        #pragma unroll
        for (int q=0;q<2*TX;q++){
          acc[ty][py][q][j4*4+0]=bv.x; acc[ty][py][q][j4*4+1]=bv.y;
          acc[ty][py][q][j4*4+2]=bv.z; acc[ty][py][q][j4*4+3]=bv.w;
        }
  }

  const bool has0 = (yy0 > 0);
  const float* nin = in + (size_t)n*PI*H*(size_t)(W*4);

  for (int pc=0; pc<PI; ++pc){
    const float* pbase = nin + (size_t)pc*H*(size_t)(W*4);
    // load TY+1 input rows (yy0-1 .. yy0+TY-1), TX+1 cols each, once
    float4 v[TY+1][TX+1];
    #pragma unroll
    for (int rr=0; rr<=TY; ++rr){
      int iy = yy0 - 1 + rr;
      bool okr = (rr>0) || has0;
      const float* rp = pbase + (size_t)(okr ? iy : 0)*(W*4);
      #pragma unroll
      for (int j=0;j<=TX;j++){
        int xi = x0 - 1 + j;
        bool ok = okr && (xi >= 0);
        float4 a = *(const float4*)(rp + (xi>=0 ? xi : 0)*4);
        if (!ok) a = zero4();
        v[rr][j] = a;
      }
    }
    const int c = pc*4;
    #pragma unroll
    for (int ty=0;ty<TY;ty++){
      #pragma unroll
      for (int ky=0;ky<3;ky++){
        const int py = (ky==1) ? 1 : 0;
        const int rsel = (ky==0) ? ty : ty+1;     // ky0 -> row yy-1; ky1,2 -> row yy
        #pragma unroll
        for (int kx=0;kx<3;kx++){
          const int pxp = (kx==1) ? 1 : 0;
          const float* wp = wlds + ((ky*3+kx)*CIN + c)*TO;
          float4 wv[4][TO/4];
          #pragma unroll
          for (int ci=0;ci<4;ci++)
            #pragma unroll
            for (int j4=0;j4<TO/4;j4++)
              wv[ci][j4] = *(const float4*)(wp + ci*TO + j4*4);
          #pragma unroll
          for (int px=0;px<TX;px++){
            const int jj = (kx==0) ? px : (px+1);
            float4 vv = v[rsel][jj];
            float vc[4] = {vv.x, vv.y, vv.z, vv.w};
            #pragma unroll
            for (int ci=0;ci<4;ci++)
              #pragma unroll
              for (int j4=0;j4<TO/4;j4++){
                acc[ty][py][2*px+pxp][j4*4+0] += vc[ci]*wv[ci][j4].x;
                acc[ty][py][2*px+pxp][j4*4+1] += vc[ci]*wv[ci][j4].y;
                acc[ty][py][2*px+pxp][j4*4+2] += vc[ci]*wv[ci][j4].z;
                acc[ty][py][2*px+pxp][j4*4+3] += vc[ci]*wv[ci][j4].w;
              }
          }
        }
      }
    }
  }

  float* nout = out + (size_t)n*PO*Ho*(size_t)(Wo*4);
  #pragma unroll
  for (int ty=0;ty<TY;ty++){
    #pragma unroll
    for (int py=0;py<2;py++){
      int yo = 2*(yy0+ty) + py;
      #pragma unroll
      for (int h2=0; h2<TO/4; ++h2){
        int pp = ob*(TO/4) + h2;
        float* op = nout + ((size_t)pp*Ho + yo)*(size_t)(Wo*4) + (size_t)(2*x0)*4;
        #pragma unroll
        for (int q=0;q<2*TX;q++){
          float4 r;
          r.x = LRELU?lrelu_f(acc[ty][py][q][h2*4+0]):acc[ty][py][q][h2*4+0];
          r.y = LRELU?lrelu_f(acc[ty][py][q][h2*4+1]):acc[ty][py][q][h2*4+1];
          r.z = LRELU?lrelu_f(acc[ty][py][q][h2*4+2]):acc[ty][py][q][h2*4+2];
          r.w = LRELU?lrelu_f(acc[ty][py][q][h2*4+3]):acc[ty][py][q][h2*4+3];
          *(float4*)(op + q*4) = r;
        }
      }
    }
  }
}

// ============ dec4: 3x3 pad-1 conv, Cout=1 — LDS-tiled, BLOCKED input (r15) ============
template<int H,int W,int CIN>
__global__ __launch_bounds__(256) void dec4_tiled_k(const float* __restrict__ in,
    const float* __restrict__ w, const float* __restrict__ bias, float* __restrict__ out){
  constexpr int TX=4, WB=128, TYB=8, GX=W/WB, GY=H/TYB, COLS=WB+2, ROWS=TYB+2;
  constexpr int NPIX = ROWS*COLS;
  constexpr int PI = CIN/4;
  __shared__ float4 tile[2*NPIX];
  __shared__ float4 wsh[(9*CIN)/4];

  int lb = swz_bid();
  int gx = lb % GX; int rest = lb / GX;
  int yg = rest % GY; int n = rest / GY;
  int xb = threadIdx.x & 31, yr = threadIdx.x >> 5;
  int y0 = yg*TYB, xbase = gx*WB;

  if (threadIdx.x < (9*CIN)/4) wsh[threadIdx.x] = ((const float4*)w)[threadIdx.x];

  const float* nin = in + (size_t)n*PI*H*(size_t)(W*4);

  float b0 = bias[0];
  float acc[TX];
  #pragma unroll
  for (int px=0;px<TX;px++) acc[px] = b0;

  for (int cc=0; cc<CIN/8; ++cc){
    __syncthreads();
    const float* p0 = nin + (size_t)(2*cc  )*H*(size_t)(W*4);
    const float* p1 = nin + (size_t)(2*cc+1)*H*(size_t)(W*4);
    for (int i = threadIdx.x; i < NPIX; i += 256){
      int row = i / COLS, col = i % COLS;
      int grow = y0 - 1 + row, gcol = xbase - 1 + col;
      float4 a0 = zero4(), a1 = zero4();
      if ((unsigned)grow < (unsigned)H && (unsigned)gcol < (unsigned)W){
        size_t off = (size_t)grow*(W*4) + (size_t)gcol*4;
        a0 = *(const float4*)(p0 + off); a1 = *(const float4*)(p1 + off);
      }
      int p = row*COLS + (col ^ ((col>>2)&7));
      tile[p] = a0; tile[NPIX + p] = a1;
    }
    __syncthreads();

    #pragma unroll
    for (int ky=0;ky<3;ky++){
      int rowb = (yr + ky)*COLS;
      float4 w0[3], w1[3];
      #pragma unroll
      for (int kx=0;kx<3;kx++){
        int tf = (ky*3+kx)*(CIN/4) + cc*2;
        w0[kx] = wsh[tf]; w1[kx] = wsh[tf+1];
      }
      #pragma unroll
      for (int j=0;j<TX+2;j++){
        int col = 4*xb + j;
        int p = rowb + (col ^ ((col>>2)&7));
        float4 a0 = tile[p], a1 = tile[NPIX + p];
        #pragma unroll
        for (int kx=0;kx<3;kx++){
          int px = j - kx;
          if (px >= 0 && px < TX){
            acc[px] += a0.x*w0[kx].x + a0.y*w0[kx].y + a0.z*w0[kx].z + a0.w*w0[kx].w
                     + a1.x*w1[kx].x + a1.y*w1[kx].y + a1.z*w1[kx].z + a1.w*w1[kx].w;
          }
        }
      }
    }
  }

  int y = y0 + yr;
  float* op = out + ((size_t)n*H + y)*(size_t)W + xbase + 4*xb;
  float4 r; r.x=acc[0]; r.y=acc[1]; r.z=acc[2]; r.w=acc[3];
  *(float4*)op = r;
}

extern "C" void kernel_launch(void* const* d_in, const int* in_sizes, int n_in,
                              void* d_out, int out_size, void* d_ws, size_t ws_size,
                              hipStream_t stream) {
  const float* x   = (const float*)d_in[0];
  const float* e1w = (const float*)d_in[1];  const float* e1b = (const float*)d_in[2];
  const float* e2w = (const float*)d_in[3];  const float* e2b = (const float*)d_in[4];
  const float* e3w = (const float*)d_in[5];  const float* e3b = (const float*)d_in[6];
  const float* e4w = (const float*)d_in[7];  const float* e4b = (const float*)d_in[8];
  const float* cb  = (const float*)d_in[9];
  const float* d1w = (const float*)d_in[10]; const float* d1b = (const float*)d_in[11];
  const float* d2w = (const float*)d_in[12]; const float* d2b = (const float*)d_in[13];
  const float* d3w = (const float*)d_in[14]; const float* d3b = (const float*)d_in[15];
  const float* d4w = (const float*)d_in[16]; const float* d4b = (const float*)d_in[17];
  float* out = (float*)d_out;

  const size_t MiB = 1ull << 20;
  int Bc = 32;
  while (Bc > 1 && (size_t)Bc * 12 * MiB > ws_size) Bc >>= 1;

  char* wsb = (char*)d_ws;
  float* A  = (float*)wsb;                              // Bc * 8 MiB
  float* Bf = (float*)(wsb + (size_t)Bc * 8 * MiB);     // Bc * 4 MiB

  for (int n0 = 0; n0 < 32; n0 += Bc) {
    const float* xc = x   + (size_t)n0 * 256*256*3;
    float*      oc  = out + (size_t)n0 * 256*256;

    // enc1: [Bc,256,256,3] -> [Bc,128,128,32] NHWC; tiled, grid = Bc*64
    enc1_tiled_k<256,256><<<Bc*64,256,0,stream>>>(xc, e1w, e1b, A);
    // enc2: -> [Bc,64,64,64] NHWC; tiled TX=2 (XC=32,ROWS=2,OBG=4,TO=16), grid = Bc*32
    conv3x3_s2_tiled_k<128,128,32,64,16,2><<<Bc*32,256,0,stream>>>(A, e2w, e2b, Bf);
    // enc3: -> [Bc,32,32,64] NHWC; tiled TX=2 (XC=16,ROWS=2,OBG=8,TO=8), grid = Bc*16
    conv3x3_s2_tiled_k<64,64,64,64,8,2><<<Bc*16,256,0,stream>>>(Bf, e3w, e3b, A);
    // enc4 (1x1, 64->32) + VQ (k-unrolled): NHWC in -> q [Bc,8,32,32,4] BLOCKED
    int npix = Bc*32*32;
    enc4_vq_k<256,64,32,64,1024><<<npix/256,256,0,stream>>>(A, e4w, e4b, cb, Bf, npix);
    // dec1: q -> d1 [Bc,16,64,64,4]; TX=1,TY=2: XB2=32,TYR=8 -> 16 rows/blk, YG=2, grid Bc*16
    deconv3x3_s2_blk_k<256,32,32,32,64,8,1,2,true><<<Bc*16,256,0,stream>>>(Bf, d1w, d1b, A);
    // dec2: -> d2 [Bc,16,128,128,4]; TX=1,TY=2: XB2=64,TYR=4 -> 8 rows/blk, YG=8, grid Bc*64
    deconv3x3_s2_blk_k<256,64,64,64,64,8,1,2,true><<<Bc*64,256,0,stream>>>(A, d2w, d2b, Bf);
    // dec3: -> d3 [Bc,8,256,256,4]; TX=2,TY=1 (r10 config): XB2=64,TYR=4,YG=32, grid Bc*128
    deconv3x3_s2_blk_k<256,128,128,64,32,8,2,1,true><<<Bc*128,256,0,stream>>>(Bf, d3w, d3b, A);
    // dec4: d3 BLOCKED -> [Bc,256,256,1]; LDS-tiled, grid Bc*64
    dec4_tiled_k<256,256,32><<<Bc*64,256,0,stream>>>(A, d4w, d4b, oc);
  }
}

// Round 19
// 922.695 us; speedup vs baseline: 1.0193x; 1.0193x over previous
//
#include <hip/hip_runtime.h>

#define ALPHA 0.2f
__device__ __forceinline__ float lrelu_f(float x){ return x>0.f ? x : ALPHA*x; }
__device__ __forceinline__ float4 zero4(){ float4 z; z.x=z.y=z.z=z.w=0.f; return z; }

// XCD-chunk swizzle: bijective iff grid%8==0; identity fallback otherwise.
__device__ __forceinline__ int swz_bid(){
  int nb = gridDim.x, b = blockIdx.x;
  return ((nb & 7)==0) ? ((b & 7)*(nb>>3) + (b>>3)) : b;
}

// ============ enc1 tiled: 3x3 s2 SAME, NHWC(3ch) -> NHWC [n,128,128,32] ============
template<int H,int W>   // 256,256
__global__ __launch_bounds__(256) void enc1_tiled_k(const float* __restrict__ in,
    const float* __restrict__ w, const float* __restrict__ bias, float* __restrict__ out){
  constexpr int Ho=H/2, Wo=W/2, COUT=32, XL=Wo, ROWS=2, IR=5, EC=XL+1, OC=XL;
  constexpr int WF4 = 9*3*(COUT/4);              // 216
  constexpr int TF4 = IR*EC + IR*OC;             // 1285
  constexpr int OUTF4 = ROWS*XL*(COUT/4);        // 2048
  constexpr int LDSF4 = (TF4+WF4 > OUTF4) ? TF4+WF4 : OUTF4;
  __shared__ float4 lds[LDSF4];
  float4* tE = lds; float4* tO = lds + IR*EC; float4* wch = lds + TF4; float4* outb = lds;

  int lb = swz_bid();
  constexpr int GYI = Ho/ROWS;                   // 64
  int yg = lb % GYI; int n = lb / GYI;
  int y0 = yg*ROWS;
  int x = threadIdx.x & (XL-1);
  int row = threadIdx.x >> 7;

  constexpr int NP = IR*(W+1);
  for (int i=threadIdx.x; i<NP; i+=256){
    int prow = i/(W+1), pcol = i%(W+1);
    int iy = 2*y0 + prow;
    bool ok = (iy<H) && (pcol<W);
    const float* sp = in + (((size_t)n*H + (ok?iy:0))*W + (ok?pcol:0))*3;
    float4 a; a.x = ok?sp[0]:0.f; a.y = ok?sp[1]:0.f; a.z = ok?sp[2]:0.f; a.w = 0.f;
    int j = pcol>>1;
    if (pcol&1) tO[prow*OC + j] = a; else tE[prow*EC + j] = a;
  }
  for (int i=threadIdx.x; i<WF4; i+=256) wch[i] = *(const float4*)(w + (size_t)i*4);
  __syncthreads();

  float acc[COUT];
  #pragma unroll
  for (int f=0;f<COUT/4;f++){
    float4 bv = *(const float4*)(bias + f*4);
    acc[f*4+0]=bv.x; acc[f*4+1]=bv.y; acc[f*4+2]=bv.z; acc[f*4+3]=bv.w;
  }

  #pragma unroll
  for (int ky=0;ky<3;ky++){
    int trow = 2*row + ky;
    #pragma unroll
    for (int kx=0;kx<3;kx++){
      int j = x + (kx==2 ? 1 : 0);
      float4 a = (kx==1) ? tO[trow*OC + j] : tE[trow*EC + j];
      float vs[3] = {a.x, a.y, a.z};
      int tap = ky*3+kx;
      #pragma unroll
      for (int ci=0;ci<3;ci++){
        float v = vs[ci];
        const float4* wp = wch + (tap*3+ci)*(COUT/4);
        #pragma unroll
        for (int f=0;f<COUT/4;f++){
          float4 wv = wp[f];
          acc[f*4+0] += v*wv.x; acc[f*4+1] += v*wv.y;
          acc[f*4+2] += v*wv.z; acc[f*4+3] += v*wv.w;
        }
      }
    }
  }

  __syncthreads();
  int px = row*XL + x;
  #pragma unroll
  for (int f=0;f<COUT/4;f++){
    float4 r;
    r.x=lrelu_f(acc[f*4+0]); r.y=lrelu_f(acc[f*4+1]);
    r.z=lrelu_f(acc[f*4+2]); r.w=lrelu_f(acc[f*4+3]);
    outb[px*(COUT/4) + (f ^ (x & 7))] = r;
  }
  __syncthreads();
  const size_t obase = (((size_t)n*Ho + y0)*(size_t)Wo)*COUT;
  for (int L=threadIdx.x; L<OUTF4; L+=256){
    int p = L/(COUT/4); int sraw = L%(COUT/4);
    int xx = p & (XL-1);
    float4 v = outb[p*(COUT/4) + (sraw ^ (xx & 7))];
    *(float4*)(out + obase + (size_t)L*4) = v;
  }
}

// ============ enc2/enc3 tiled TX=2: 3x3 s2 SAME, NHWC in/out, channel-chunked ============
template<int H,int W,int CIN,int COUT,int TO,int TX>
__global__ __launch_bounds__(256) void conv3x3_s2_tiled_k(const float* __restrict__ in,
    const float* __restrict__ w, const float* __restrict__ bias, float* __restrict__ out){
  constexpr int Ho=H/2, Wo=W/2, XL=Wo, XC=XL/TX, OBG=COUT/TO, ROWS=256/(XC*OBG);
  static_assert(ROWS==2 && XC*ROWS*OBG==256, "geometry");
  constexpr int IR = 5, EC = XL+1, OC = XL, CC = CIN/8;
  constexpr int WF4 = 9*8*(COUT/4);
  constexpr int TF4 = 2*IR*EC + 2*IR*OC;
  constexpr int OUTF4 = ROWS*XL*(COUT/4);
  constexpr int LDSF4 = (TF4+WF4 > OUTF4) ? TF4+WF4 : OUTF4;
  __shared__ float4 lds[LDSF4];
  float4* tE = lds;                       // [2][IR][EC]
  float4* tO = lds + 2*IR*EC;             // [2][IR][OC]
  float4* wch = lds + TF4;                // [9*8][COUT/4]
  float4* outb = lds;

  int lb = swz_bid();
  constexpr int GYI = Ho/ROWS;
  int yg = lb % GYI; int n = lb / GYI;
  int y0 = yg*ROWS;
  int xc = threadIdx.x % XC;
  int r = threadIdx.x / XC;
  int row = r % ROWS, ob = r / ROWS;      // ob wave-uniform or 2-way (free broadcast)

  float acc[TX][TO];
  #pragma unroll
  for (int f=0;f<TO/4;f++){
    float4 bv = *(const float4*)(bias + ob*TO + f*4);
    #pragma unroll
    for (int t=0;t<TX;t++){
      acc[t][f*4+0]=bv.x; acc[t][f*4+1]=bv.y; acc[t][f*4+2]=bv.z; acc[t][f*4+3]=bv.w;
    }
  }

  constexpr int NP = IR*(W+1);
  for (int cc=0; cc<CC; ++cc){
    __syncthreads();
    for (int i=threadIdx.x; i<NP; i+=256){
      int prow = i/(W+1), pcol = i%(W+1);
      int iy = 2*y0 + prow;
      bool ok = (iy<H) && (pcol<W);
      const float* sp = in + (((size_t)n*H + (ok?iy:0))*W + (ok?pcol:0))*CIN + cc*8;
      float4 a0 = ok ? *(const float4*)sp     : zero4();
      float4 a1 = ok ? *(const float4*)(sp+4) : zero4();
      int j = pcol>>1;
      if (pcol&1){ tO[(0*IR+prow)*OC + j] = a0; tO[(1*IR+prow)*OC + j] = a1; }
      else       { tE[(0*IR+prow)*EC + j] = a0; tE[(1*IR+prow)*EC + j] = a1; }
    }
    for (int i=threadIdx.x; i<WF4; i+=256){
      int co4 = i % (COUT/4); int rest = i/(COUT/4);   // rest = tap*8+ci
      int ci = rest % 8, tap = rest/8;
      wch[i] = *(const float4*)(w + ((size_t)(tap*CIN + cc*8+ci))*COUT + co4*4);
    }
    __syncthreads();
    #pragma unroll
    for (int ky=0;ky<3;ky++){
      int trow = 2*row + ky;
      #pragma unroll
      for (int kx=0;kx<3;kx++){
        float vs[TX][8];
        #pragma unroll
        for (int t=0;t<TX;t++){
          int j = (xc + t*XC) + (kx==2 ? 1 : 0);
          float4 a0, a1;
          if (kx==1){ a0 = tO[(0*IR+trow)*OC + j]; a1 = tO[(1*IR+trow)*OC + j]; }
          else      { a0 = tE[(0*IR+trow)*EC + j]; a1 = tE[(1*IR+trow)*EC + j]; }
          vs[t][0]=a0.x; vs[t][1]=a0.y; vs[t][2]=a0.z; vs[t][3]=a0.w;
          vs[t][4]=a1.x; vs[t][5]=a1.y; vs[t][6]=a1.z; vs[t][7]=a1.w;
        }
        int tap = ky*3+kx;
        #pragma unroll
        for (int ci=0;ci<8;ci++){
          const float4* wp = wch + (tap*8+ci)*(COUT/4) + ob*(TO/4);
          #pragma unroll
          for (int f=0;f<TO/4;f++){
            float4 wv = wp[f];
            #pragma unroll
            for (int t=0;t<TX;t++){
              float v = vs[t][ci];
              acc[t][f*4+0] += v*wv.x; acc[t][f*4+1] += v*wv.y;
              acc[t][f*4+2] += v*wv.z; acc[t][f*4+3] += v*wv.w;
            }
          }
        }
      }
    }
  }

  __syncthreads();                        // all reads done; outb aliases lds
  #pragma unroll
  for (int t=0;t<TX;t++){
    int x = xc + t*XC;
    int px = row*XL + x;
    #pragma unroll
    for (int f=0;f<TO/4;f++){
      float4 r2;
      r2.x=lrelu_f(acc[t][f*4+0]); r2.y=lrelu_f(acc[t][f*4+1]);
      r2.z=lrelu_f(acc[t][f*4+2]); r2.w=lrelu_f(acc[t][f*4+3]);
      int slot = (ob*(TO/4)+f) ^ (x & 15);
      outb[px*(COUT/4) + slot] = r2;
    }
  }
  __syncthreads();
  const size_t obase = (((size_t)n*Ho + y0)*(size_t)Wo)*COUT;
  for (int L=threadIdx.x; L<OUTF4; L+=256){
    int p = L/(COUT/4); int sraw = L%(COUT/4);
    int xx = p % XL;
    float4 v = outb[p*(COUT/4) + (sraw ^ (xx & 15))];
    *(float4*)(out + obase + (size_t)L*4) = v;
  }
}

// ============ Fused enc4 (1x1 conv 64->32) + VQ; k-loop unrolled x4 (ILP) ============
template<int TPB,int CIN,int D,int K,int PIXI>
__global__ __launch_bounds__(TPB) void enc4_vq_k(const float* __restrict__ in,
    const float* __restrict__ w, const float* __restrict__ bias,
    const float* __restrict__ cb, float* __restrict__ q, int npix){
  int i = blockIdx.x*TPB + threadIdx.x;
  if (i >= npix) return;
  const float* ip = in + (size_t)i*CIN;
  float z[D];
  #pragma unroll
  for (int d=0; d<D; d++) z[d] = bias[d];
  for (int c=0; c<CIN; c+=4){
    float4 v = *(const float4*)(ip + c);
    #pragma unroll
    for (int d=0; d<D; d++){
      z[d] += v.x * w[(c+0)*D + d];
      z[d] += v.y * w[(c+1)*D + d];
      z[d] += v.z * w[(c+2)*D + d];
      z[d] += v.w * w[(c+3)*D + d];
    }
  }
  float z2 = 0.f;
  #pragma unroll
  for (int d=0; d<D; d++) z2 += z[d]*z[d];

  float bestd[4]; int bestk[4];
  #pragma unroll
  for (int j=0;j<4;j++){ bestd[j]=3.4e38f; bestk[j]=0; }
  for (int k=0; k<K; k+=4){
    float e2a[4]={0.f,0.f,0.f,0.f}, dota[4]={0.f,0.f,0.f,0.f};
    #pragma unroll
    for (int d=0; d<D; d++){
      float zd = z[d];
      float4 cv = *(const float4*)(cb + d*K + k);
      e2a[0]+=cv.x*cv.x; dota[0]+=zd*cv.x;
      e2a[1]+=cv.y*cv.y; dota[1]+=zd*cv.y;
      e2a[2]+=cv.z*cv.z; dota[2]+=zd*cv.z;
      e2a[3]+=cv.w*cv.w; dota[3]+=zd*cv.w;
    }
    #pragma unroll
    for (int j=0;j<4;j++){
      float dist = z2 + e2a[j] - 2.f*dota[j];
      if (dist < bestd[j]){ bestd[j]=dist; bestk[j]=k+j; }   // first-min in residue class
    }
  }
  float best = bestd[0]; int bi = bestk[0];
  #pragma unroll
  for (int j=1;j<4;j++){
    if (bestd[j] < best || (bestd[j] == best && bestk[j] < bi)){ best=bestd[j]; bi=bestk[j]; }
  }

  int n = i / PIXI, pix = i % PIXI;
  #pragma unroll
  for (int p=0; p<D/4; p++){
    float4 f;
    f.x = cb[(4*p+0)*K + bi]; f.y = cb[(4*p+1)*K + bi];
    f.z = cb[(4*p+2)*K + bi]; f.w = cb[(4*p+3)*K + bi];
    *(float4*)(q + ((size_t)(n*(D/4)+p)*PIXI + pix)*4) = f;   // coalesced per plane
  }
}

// ======== Parity-fused deconv 3x3 s2 SAME, BLOCKED in/out (r10 verified config) ========
template<int TPB,int H,int W,int CIN,int COUT,int TO,int TX,bool LRELU>
__global__ __launch_bounds__(TPB) void deconv3x3_s2_blk_k(const float* __restrict__ in,
    const float* __restrict__ w, const float* __restrict__ bias, float* __restrict__ out){
  constexpr int Ho=2*H, Wo=2*W, OB=COUT/TO, XB2=W/TX, TYR=TPB/XB2, YG=H/TYR;
  constexpr int PI=CIN/4, PO=COUT/4;
  constexpr int WN = 9*CIN*TO;
  static_assert(TPB % XB2 == 0 && H % TYR == 0, "geometry");
  __shared__ float wlds[WN];

  int lb = swz_bid();
  int ob = lb % OB; int g = lb / OB;
  int yg = g % YG;  int n  = g / YG;
  int xb = threadIdx.x % XB2, yr = threadIdx.x / XB2;
  int yy = yg*TYR + yr, x0 = xb*TX;

  {
    const int base = ob*TO;
    for (int i = threadIdx.x; i < WN/4; i += TPB){
      int j4 = i % (TO/4); int rest = i / (TO/4);
      ((float4*)wlds)[i] = *(const float4*)(w + (size_t)rest*COUT + base + j4*4);
    }
  }
  __syncthreads();

  float acc[2][2*TX][TO];
  #pragma unroll
  for (int j4=0;j4<TO/4;j4++){
    float4 bv = *(const float4*)(bias + ob*TO + j4*4);
    #pragma unroll
    for (int py=0;py<2;py++)
      #pragma unroll
      for (int q=0;q<2*TX;q++){
        acc[py][q][j4*4+0]=bv.x; acc[py][q][j4*4+1]=bv.y;
        acc[py][q][j4*4+2]=bv.z; acc[py][q][j4*4+3]=bv.w;
      }
  }

  const bool has0 = (yy > 0);
  const float* nin = in + (size_t)n*PI*H*(size_t)(W*4);

  for (int pc=0; pc<PI; ++pc){
    const float* pbase = nin + (size_t)pc*H*(size_t)(W*4);
    const float* r1p = pbase + (size_t)yy*(W*4);
    const float* r0p = pbase + (size_t)(has0 ? yy-1 : 0)*(W*4);
    float4 v0[TX+1], v1[TX+1];
    #pragma unroll
    for (int j=0;j<=TX;j++){
      int xi = x0 - 1 + j;
      bool ok = (xi >= 0);
      int off = (ok ? xi : 0)*4;
      float4 a1 = *(const float4*)(r1p + off);
      float4 a0 = has0 ? *(const float4*)(r0p + off) : zero4();
      if (!ok){ a1 = zero4(); a0 = zero4(); }
      v1[j] = a1; v0[j] = a0;
    }
    const int c = pc*4;
    #pragma unroll
    for (int ky=0;ky<3;ky++){
      const int py = (ky==1) ? 1 : 0;
      #pragma unroll
      for (int kx=0;kx<3;kx++){
        const int pxp = (kx==1) ? 1 : 0;
        const float* wp = wlds + ((ky*3+kx)*CIN + c)*TO;
        float4 wv[4][TO/4];
        #pragma unroll
        for (int ci=0;ci<4;ci++)
          #pragma unroll
          for (int j4=0;j4<TO/4;j4++)
            wv[ci][j4] = *(const float4*)(wp + ci*TO + j4*4);
        #pragma unroll
        for (int px=0;px<TX;px++){
          const int jj = (kx==0) ? px : (px+1);
          float4 vv = (ky==0) ? v0[jj] : v1[jj];
          float vc[4] = {vv.x, vv.y, vv.z, vv.w};
          #pragma unroll
          for (int ci=0;ci<4;ci++)
            #pragma unroll
            for (int j4=0;j4<TO/4;j4++){
              acc[py][2*px+pxp][j4*4+0] += vc[ci]*wv[ci][j4].x;
              acc[py][2*px+pxp][j4*4+1] += vc[ci]*wv[ci][j4].y;
              acc[py][2*px+pxp][j4*4+2] += vc[ci]*wv[ci][j4].z;
              acc[py][2*px+pxp][j4*4+3] += vc[ci]*wv[ci][j4].w;
            }
        }
      }
    }
  }

  float* nout = out + (size_t)n*PO*Ho*(size_t)(Wo*4);
  #pragma unroll
  for (int py=0;py<2;py++){
    int yo = 2*yy + py;
    #pragma unroll
    for (int h2=0; h2<TO/4; ++h2){
      int pp = ob*(TO/4) + h2;
      float* op = nout + ((size_t)pp*Ho + yo)*(size_t)(Wo*4) + (size_t)(2*x0)*4;
      #pragma unroll
      for (int q=0;q<2*TX;q++){
        float4 r;
        r.x = LRELU?lrelu_f(acc[py][q][h2*4+0]):acc[py][q][h2*4+0];
        r.y = LRELU?lrelu_f(acc[py][q][h2*4+1]):acc[py][q][h2*4+1];
        r.z = LRELU?lrelu_f(acc[py][q][h2*4+2]):acc[py][q][h2*4+2];
        r.w = LRELU?lrelu_f(acc[py][q][h2*4+3]):acc[py][q][h2*4+3];
        *(float4*)(op + q*4) = r;
      }
    }
  }
}

// ============ dec4: 3x3 pad-1 conv, Cout=1 — LDS-tiled, BLOCKED input ============
template<int H,int W,int CIN>
__global__ __launch_bounds__(256) void dec4_tiled_k(const float* __restrict__ in,
    const float* __restrict__ w, const float* __restrict__ bias, float* __restrict__ out){
  constexpr int TX=4, WB=128, TYB=8, GX=W/WB, GY=H/TYB, COLS=WB+2, ROWS=TYB+2;
  constexpr int NPIX = ROWS*COLS;
  constexpr int PI = CIN/4;
  __shared__ float4 tile[2*NPIX];
  __shared__ float4 wsh[(9*CIN)/4];

  int lb = swz_bid();
  int gx = lb % GX; int rest = lb / GX;
  int yg = rest % GY; int n = rest / GY;
  int xb = threadIdx.x & 31, yr = threadIdx.x >> 5;
  int y0 = yg*TYB, xbase = gx*WB;

  if (threadIdx.x < (9*CIN)/4) wsh[threadIdx.x] = ((const float4*)w)[threadIdx.x];

  const float* nin = in + (size_t)n*PI*H*(size_t)(W*4);

  float b0 = bias[0];
  float acc[TX];
  #pragma unroll
  for (int px=0;px<TX;px++) acc[px] = b0;

  for (int cc=0; cc<CIN/8; ++cc){
    __syncthreads();
    const float* p0 = nin + (size_t)(2*cc  )*H*(size_t)(W*4);
    const float* p1 = nin + (size_t)(2*cc+1)*H*(size_t)(W*4);
    for (int i = threadIdx.x; i < NPIX; i += 256){
      int row = i / COLS, col = i % COLS;
      int grow = y0 - 1 + row, gcol = xbase - 1 + col;
      float4 a0 = zero4(), a1 = zero4();
      if ((unsigned)grow < (unsigned)H && (unsigned)gcol < (unsigned)W){
        size_t off = (size_t)grow*(W*4) + (size_t)gcol*4;
        a0 = *(const float4*)(p0 + off); a1 = *(const float4*)(p1 + off);
      }
      int p = row*COLS + (col ^ ((col>>2)&7));
      tile[p] = a0; tile[NPIX + p] = a1;
    }
    __syncthreads();

    #pragma unroll
    for (int ky=0;ky<3;ky++){
      int rowb = (yr + ky)*COLS;
      float4 w0[3], w1[3];
      #pragma unroll
      for (int kx=0;kx<3;kx++){
        int tf = (ky*3+kx)*(CIN/4) + cc*2;
        w0[kx] = wsh[tf]; w1[kx] = wsh[tf+1];
      }
      #pragma unroll
      for (int j=0;j<TX+2;j++){
        int col = 4*xb + j;
        int p = rowb + (col ^ ((col>>2)&7));
        float4 a0 = tile[p], a1 = tile[NPIX + p];
        #pragma unroll
        for (int kx=0;kx<3;kx++){
          int px = j - kx;
          if (px >= 0 && px < TX){
            acc[px] += a0.x*w0[kx].x + a0.y*w0[kx].y + a0.z*w0[kx].z + a0.w*w0[kx].w
                     + a1.x*w1[kx].x + a1.y*w1[kx].y + a1.z*w1[kx].z + a1.w*w1[kx].w;
          }
        }
      }
    }
  }

  int y = y0 + yr;
  float* op = out + ((size_t)n*H + y)*(size_t)W + xbase + 4*xb;
  float4 r; r.x=acc[0]; r.y=acc[1]; r.z=acc[2]; r.w=acc[3];
  *(float4*)op = r;
}

extern "C" void kernel_launch(void* const* d_in, const int* in_sizes, int n_in,
                              void* d_out, int out_size, void* d_ws, size_t ws_size,
                              hipStream_t stream) {
  const float* x   = (const float*)d_in[0];
  const float* e1w = (const float*)d_in[1];  const float* e1b = (const float*)d_in[2];
  const float* e2w = (const float*)d_in[3];  const float* e2b = (const float*)d_in[4];
  const float* e3w = (const float*)d_in[5];  const float* e3b = (const float*)d_in[6];
  const float* e4w = (const float*)d_in[7];  const float* e4b = (const float*)d_in[8];
  const float* cb  = (const float*)d_in[9];
  const float* d1w = (const float*)d_in[10]; const float* d1b = (const float*)d_in[11];
  const float* d2w = (const float*)d_in[12]; const float* d2b = (const float*)d_in[13];
  const float* d3w = (const float*)d_in[14]; const float* d3b = (const float*)d_in[15];
  const float* d4w = (const float*)d_in[16]; const float* d4b = (const float*)d_in[17];
  float* out = (float*)d_out;

  const size_t MiB = 1ull << 20;
  int Bc = 32;
  while (Bc > 1 && (size_t)Bc * 12 * MiB > ws_size) Bc >>= 1;

  char* wsb = (char*)d_ws;
  float* A  = (float*)wsb;                              // Bc * 8 MiB
  float* Bf = (float*)(wsb + (size_t)Bc * 8 * MiB);     // Bc * 4 MiB

  for (int n0 = 0; n0 < 32; n0 += Bc) {
    const float* xc = x   + (size_t)n0 * 256*256*3;
    float*      oc  = out + (size_t)n0 * 256*256;

    // enc1: [Bc,256,256,3] -> [Bc,128,128,32] NHWC; tiled, grid = Bc*64
    enc1_tiled_k<256,256><<<Bc*64,256,0,stream>>>(xc, e1w, e1b, A);
    // enc2: -> [Bc,64,64,64] NHWC; tiled TX=2 (XC=32,ROWS=2,OBG=4,TO=16), grid = Bc*32
    conv3x3_s2_tiled_k<128,128,32,64,16,2><<<Bc*32,256,0,stream>>>(A, e2w, e2b, Bf);
    // enc3: -> [Bc,32,32,64] NHWC; tiled TX=2 (XC=16,ROWS=2,OBG=8,TO=8), grid = Bc*16
    conv3x3_s2_tiled_k<64,64,64,64,8,2><<<Bc*16,256,0,stream>>>(Bf, e3w, e3b, A);
    // enc4 (1x1, 64->32) + VQ (k-unrolled): NHWC in -> q [Bc,8,32,32,4] BLOCKED
    int npix = Bc*32*32;
    enc4_vq_k<256,64,32,64,1024><<<npix/256,256,0,stream>>>(A, e4w, e4b, cb, Bf, npix);
    // dec1: q -> d1 [Bc,16,64,64,4]; TX=1: XB2=32,TYR=8,YG=4,OB=8 -> Bc*32 (r10)
    deconv3x3_s2_blk_k<256,32,32,32,64,8,1,true><<<Bc*32,256,0,stream>>>(Bf, d1w, d1b, A);
    // dec2: -> d2 [Bc,16,128,128,4]; TX=1: XB2=64,TYR=4,YG=16,OB=8 -> Bc*128 (r10)
    deconv3x3_s2_blk_k<256,64,64,64,64,8,1,true><<<Bc*128,256,0,stream>>>(A, d2w, d2b, Bf);
    // dec3: -> d3 [Bc,8,256,256,4]; TX=2: XB2=64,TYR=4,YG=32,OB=4 -> Bc*128 (r10)
    deconv3x3_s2_blk_k<256,128,128,64,32,8,2,true><<<Bc*128,256,0,stream>>>(Bf, d3w, d3b, A);
    // dec4: d3 BLOCKED -> [Bc,256,256,1]; LDS-tiled, grid Bc*64
    dec4_tiled_k<256,256,32><<<Bc*64,256,0,stream>>>(A, d4w, d4b, oc);
  }
}